// Round 6
// baseline (770.622 us; speedup 1.0000x reference)
//
#include <hip/hip_runtime.h>

#define N_NODES 100000
#define N_EDGES 1600000
#define CAP 64     // max in-degree slots; P(Binom(1.6M,1e-5) >= 64) ~ 3e-22/node
#define GB 6250    // N_EDGES / 256 (exact)
#define GM 782     // ceil(N_NODES / 128)

typedef short short8 __attribute__((ext_vector_type(8)));
typedef float f32x4 __attribute__((ext_vector_type(4)));

__device__ __forceinline__ unsigned short f2b(float f) {
    unsigned u = __builtin_bit_cast(unsigned, f);
    u += 0x7fffu + ((u >> 16) & 1u);          // RNE
    return (unsigned short)(u >> 16);
}
__device__ __forceinline__ float b2f_lo(unsigned p) {
    return __builtin_bit_cast(float, p << 16);
}
__device__ __forceinline__ float b2f_hi(unsigned p) {
    return __builtin_bit_cast(float, p & 0xffff0000u);
}

// ---------------- FAT kernel: CSR build  ||  mm1 (x @ [W1|W2|W0-W2])  ||  Wt2/Wt3 prep ----------------
// These are the only mutually independent pieces of the pipeline; build is atomic-bound
// (11% HBM, 0.4% VALU) so mm1's MFMA/BW blocks co-schedule under it nearly free.
// Block ranges: [0,GB) build | [GB,GB+3*GM) mm1 (slice=bid/GM) | 96 Wt2 blocks | 384 Wt3 blocks.
__global__ __launch_bounds__(256) void k_fat(const int* __restrict__ src, const int* __restrict__ dst,
                                             float* __restrict__ degout, int* __restrict__ cnt,
                                             int* __restrict__ slots,
                                             const float* __restrict__ x, const float* __restrict__ W1,
                                             const float* __restrict__ b1,
                                             const float* __restrict__ W2, const float* __restrict__ W3,
                                             unsigned short* __restrict__ vub,
                                             unsigned short* __restrict__ Wt2,
                                             unsigned short* __restrict__ Wt3) {
    constexpr int KT = 128, KP = KT + 8, NFR = 4;
    __shared__ unsigned short sw[64 * KP];
    const int tid = threadIdx.x;
    int bid = blockIdx.x;

    if (bid < GB) {
        // ---- fused degree-count + direct-slot CSR build (atomic-RMW-bound) ----
        int e = bid * 256 + tid;
        int s = src[e], d = dst[e];
        if (s != d) {
            atomicAdd(&degout[s], 1.0f);
            int pos = atomicAdd(&cnt[d], 1);
            if (pos < CAP) slots[(size_t)d * CAP + pos] = s;   // guard never fires in practice
        }
        return;
    }
    bid -= GB;
    if (bid < 3 * GM) {
        // ---- mm1: vub[N][192] = x @ [W1[1] | W1[2] | W1[0]-W1[2]] (+b1 on base cols) ----
        // Wt1m transform + bias computed INLINE (no dependency on a prep kernel).
        const int sl = bid / GM, mb = bid % GM;
        const int n0 = sl * 64;

        // stage virtual Wt1m rows n0..n0+63 into LDS with on-the-fly transform
        // consecutive 64 threads read consecutive co -> coalesced; branch is block-uniform.
        for (int i = tid; i < 64 * 128; i += 256) {
            int k = i >> 6;
            int r = i & 63;
            int co = r + n0;
            float v;
            if (co < 64)       v = W1[(128 + k) * 64 + co];
            else if (co < 128) v = W1[(256 + k) * 64 + (co - 64)];
            else               v = W1[k * 64 + (co - 128)] - W1[(256 + k) * 64 + (co - 128)];
            sw[r * KP + k] = f2b(v);
        }
        __syncthreads();

        const int wave = tid >> 6, lane = tid & 63;
        const int l16 = lane & 15, quad = lane >> 4;
        const int mBase = mb * 128 + wave * 32;
        const int r0 = mBase + l16, r1 = mBase + 16 + l16;
        const bool in0 = r0 < N_NODES, in1 = r1 < N_NODES;

        f32x4 acc[2][NFR] = {};
        const short8 zero8 = {0, 0, 0, 0, 0, 0, 0, 0};

        #pragma unroll
        for (int kt = 0; kt < KT / 32; kt++) {
            const int kin = kt * 32 + quad * 8;
            short8 a0 = zero8, a1 = zero8;
            if (in0) {
                const float* px = x + (size_t)r0 * 128 + kin;
                float4 f0 = *(const float4*)px, f1 = *(const float4*)(px + 4);
                a0[0] = (short)f2b(f0.x); a0[1] = (short)f2b(f0.y);
                a0[2] = (short)f2b(f0.z); a0[3] = (short)f2b(f0.w);
                a0[4] = (short)f2b(f1.x); a0[5] = (short)f2b(f1.y);
                a0[6] = (short)f2b(f1.z); a0[7] = (short)f2b(f1.w);
            }
            if (in1) {
                const float* px = x + (size_t)r1 * 128 + kin;
                float4 f0 = *(const float4*)px, f1 = *(const float4*)(px + 4);
                a1[0] = (short)f2b(f0.x); a1[1] = (short)f2b(f0.y);
                a1[2] = (short)f2b(f0.z); a1[3] = (short)f2b(f0.w);
                a1[4] = (short)f2b(f1.x); a1[5] = (short)f2b(f1.y);
                a1[6] = (short)f2b(f1.z); a1[7] = (short)f2b(f1.w);
            }
            #pragma unroll
            for (int nf = 0; nf < NFR; nf++) {
                const short8 b = *(const short8*)(sw + (nf * 16 + l16) * KP + kt * 32 + quad * 8);
                acc[0][nf] = __builtin_amdgcn_mfma_f32_16x16x32_bf16(a0, b, acc[0][nf], 0, 0, 0);
                acc[1][nf] = __builtin_amdgcn_mfma_f32_16x16x32_bf16(a1, b, acc[1][nf], 0, 0, 0);
            }
        }

        #pragma unroll
        for (int mi = 0; mi < 2; mi++) {
            #pragma unroll
            for (int nf = 0; nf < NFR; nf++) {
                #pragma unroll
                for (int r = 0; r < 4; r++) {
                    const int node = mBase + mi * 16 + quad * 4 + r;
                    if (node < N_NODES) {
                        const int co = n0 + nf * 16 + l16;
                        float o = acc[mi][nf][r] + (co >= 128 ? b1[co - 128] : 0.f);
                        vub[(size_t)node * 192 + co] = f2b(o);
                    }
                }
            }
        }
        return;
    }
    bid -= 3 * GM;
    if (bid < 96) {
        // ---- Wt2[128][192] = transpose(W2) bf16 ----
        int j = bid * 256 + tid;                 // < 24576
        int k = j % 192, n = j / 192;
        Wt2[(size_t)n * 192 + k] = f2b(W2[(size_t)k * 128 + n]);
        return;
    }
    bid -= 96;
    {
        // ---- Wt3[256][384] = transpose(W3) bf16 ----
        int j = bid * 256 + tid;                 // < 98304
        int k = j % 384, n = j / 384;
        Wt3[(size_t)n * 384 + k] = f2b(W3[(size_t)k * 256 + n]);
    }
}

__global__ void k_dinv(float* __restrict__ deg) {
    int n = blockIdx.x * blockDim.x + threadIdx.x;
    if (n < N_NODES) {
        float dg = deg[n];
        deg[n] = dg > 0.f ? rsqrtf(dg) : 0.f;
    }
}

// ---------------- gather v7: 8-deep unroll padded to mhi (no serial remainder) ----------------
// out[n] = (-alpha*dinv[n]) * sum_e dinv[c]*h[c]  (+ beta*init[n]); fp32 accum.
// 2 nodes per wave (lanes 0..31 -> n0, 32..63 -> n1). Lanes past a node's degree
// are staged c=0,w=0 -> spurious iterations read L1-hot row 0 and fmaf(0,.) (exact no-op).
template <int C, bool RELU>
__global__ __launch_bounds__(256) void k_gather7(const unsigned short* __restrict__ h,
                                                 int hStride,
                                                 const int* __restrict__ cnt,
                                                 const int* __restrict__ slots,
                                                 const float* __restrict__ dinv,
                                                 float alpha,
                                                 const unsigned short* __restrict__ init,
                                                 int iStride,
                                                 float beta,
                                                 unsigned short* __restrict__ out) {
    const int wave = threadIdx.x >> 6;
    const int lane = threadIdx.x & 63;
    const int half = lane >> 5;
    const int l32  = lane & 31;
    const int n0 = (blockIdx.x * 4 + wave) * 2;   // N_NODES even -> n1 always valid
    if (n0 >= N_NODES) return;
    const int n1 = n0 + 1;
    const int m0 = min(cnt[n0], CAP);
    const int m1 = min(cnt[n1], CAP);
    const int nMy = half ? n1 : n0;

    // full-wave slot staging: lane j holds slot j of each node (c=0,w=0 past degree)
    int c0l = 0, c1l = 0;
    float w0f = 0.f, w1f = 0.f;
    if (lane < m0) { c0l = slots[(size_t)n0 * CAP + lane]; w0f = dinv[c0l]; }
    if (lane < m1) { c1l = slots[(size_t)n1 * CAP + lane]; w1f = dinv[c1l]; }
    const int w0i = __builtin_bit_cast(int, w0f);
    const int w1i = __builtin_bit_cast(int, w1f);

    const int mhi = max(m0, m1);
    const float scale = -alpha * dinv[nMy];

    if (C == 128) {
        const uint2* h4 = (const uint2*)h;
        float ax = 0.f, ay = 0.f, az = 0.f, aw = 0.f;
        for (int j = 0; j < mhi; j += 8) {
            #pragma unroll
            for (int k = 0; k < 8; k++) {
                int cA = __builtin_amdgcn_readlane(c0l, j + k);
                int cB = __builtin_amdgcn_readlane(c1l, j + k);
                float wA = __builtin_bit_cast(float, __builtin_amdgcn_readlane(w0i, j + k));
                float wB = __builtin_bit_cast(float, __builtin_amdgcn_readlane(w1i, j + k));
                int c = half ? cB : cA;
                float w = half ? wB : wA;
                uint2 q = h4[(size_t)c * hStride + l32];
                ax = fmaf(w, b2f_lo(q.x), ax); ay = fmaf(w, b2f_hi(q.x), ay);
                az = fmaf(w, b2f_lo(q.y), az); aw = fmaf(w, b2f_hi(q.y), aw);
            }
        }
        float vx = scale * ax, vy = scale * ay, vz = scale * az, vw = scale * aw;
        if (init) {
            uint2 ip = ((const uint2*)init)[(size_t)nMy * iStride + l32];
            vx = fmaf(beta, b2f_lo(ip.x), vx); vy = fmaf(beta, b2f_hi(ip.x), vy);
            vz = fmaf(beta, b2f_lo(ip.y), vz); vw = fmaf(beta, b2f_hi(ip.y), vw);
        }
        if (RELU) {
            vx = fmaxf(vx, 0.f); vy = fmaxf(vy, 0.f);
            vz = fmaxf(vz, 0.f); vw = fmaxf(vw, 0.f);
        }
        uint2 o;
        o.x = (unsigned)f2b(vx) | ((unsigned)f2b(vy) << 16);
        o.y = (unsigned)f2b(vz) | ((unsigned)f2b(vw) << 16);
        ((uint2*)out)[(size_t)nMy * 32 + l32] = o;
    } else {   // C == 64
        const unsigned* h2 = (const unsigned*)h;
        float ax = 0.f, ay = 0.f;
        for (int j = 0; j < mhi; j += 8) {
            #pragma unroll
            for (int k = 0; k < 8; k++) {
                int cA = __builtin_amdgcn_readlane(c0l, j + k);
                int cB = __builtin_amdgcn_readlane(c1l, j + k);
                float wA = __builtin_bit_cast(float, __builtin_amdgcn_readlane(w0i, j + k));
                float wB = __builtin_bit_cast(float, __builtin_amdgcn_readlane(w1i, j + k));
                int c = half ? cB : cA;
                float w = half ? wB : wA;
                unsigned q = h2[(size_t)c * hStride + l32];
                ax = fmaf(w, b2f_lo(q), ax); ay = fmaf(w, b2f_hi(q), ay);
            }
        }
        float vx = scale * ax, vy = scale * ay;
        if (init) {
            unsigned ip = ((const unsigned*)init)[(size_t)nMy * iStride + l32];
            vx = fmaf(beta, b2f_lo(ip), vx); vy = fmaf(beta, b2f_hi(ip), vy);
        }
        if (RELU) { vx = fmaxf(vx, 0.f); vy = fmaxf(vy, 0.f); }
        ((unsigned*)out)[(size_t)nMy * 32 + l32] =
            (unsigned)f2b(vx) | ((unsigned)f2b(vy) << 16);
    }
}

// ---------------- MFMA GEMM v2: LDS-staged Wt N-slice, 128-row blocks ----------------
template <int CIN, int COUT, int NSL, bool RELU, bool BF16OUT>
__global__ __launch_bounds__(256) void k_mm2(const unsigned short* __restrict__ t0,
                                             const unsigned short* __restrict__ t1,
                                             const unsigned short* __restrict__ t2,
                                             const unsigned short* __restrict__ Wt,
                                             const float* __restrict__ bias,
                                             void* __restrict__ outv) {
    constexpr int KT = 3 * CIN;
    constexpr int KP = KT + 8;
    constexpr int NFR = NSL / 16;
    __shared__ unsigned short sw[NSL * KP];

    const int tid = threadIdx.x;
    const int n0 = blockIdx.y * NSL;

    constexpr int CHUNKS = NSL * KT / 8;
    for (int i = tid; i < CHUNKS; i += 256) {
        int row = i / (KT / 8);
        int k8 = i % (KT / 8);
        short8 v = *(const short8*)(Wt + (size_t)(n0 + row) * KT + k8 * 8);
        *(short8*)(sw + row * KP + k8 * 8) = v;
    }
    __syncthreads();

    const int wave = tid >> 6, lane = tid & 63;
    const int l16 = lane & 15, quad = lane >> 4;
    const int mBase = blockIdx.x * 128 + wave * 32;
    const int r0 = mBase + l16, r1 = mBase + 16 + l16;
    const bool in0 = r0 < N_NODES, in1 = r1 < N_NODES;

    f32x4 acc[2][NFR] = {};
    const unsigned short* tb[3] = {t0, t1, t2};
    const short8 zero8 = {0, 0, 0, 0, 0, 0, 0, 0};

    #pragma unroll
    for (int kt = 0; kt < KT / 32; kt++) {
        const int kb = kt * 32;
        const unsigned short* t = tb[kb / CIN];
        const int kin = (kb % CIN) + quad * 8;
        short8 a0 = zero8, a1 = zero8;
        if (in0) a0 = *(const short8*)(t + (size_t)r0 * CIN + kin);
        if (in1) a1 = *(const short8*)(t + (size_t)r1 * CIN + kin);
        #pragma unroll
        for (int nf = 0; nf < NFR; nf++) {
            const short8 b = *(const short8*)(sw + (nf * 16 + l16) * KP + kb + quad * 8);
            acc[0][nf] = __builtin_amdgcn_mfma_f32_16x16x32_bf16(a0, b, acc[0][nf], 0, 0, 0);
            acc[1][nf] = __builtin_amdgcn_mfma_f32_16x16x32_bf16(a1, b, acc[1][nf], 0, 0, 0);
        }
    }

    #pragma unroll
    for (int mi = 0; mi < 2; mi++) {
        #pragma unroll
        for (int nf = 0; nf < NFR; nf++) {
            #pragma unroll
            for (int r = 0; r < 4; r++) {
                const int node = mBase + mi * 16 + quad * 4 + r;
                if (node < N_NODES) {
                    const int co = n0 + nf * 16 + l16;
                    float o = acc[mi][nf][r] + bias[co];
                    if (RELU) o = fmaxf(o, 0.f);
                    if (BF16OUT)
                        ((unsigned short*)outv)[(size_t)node * COUT + co] = f2b(o);
                    else
                        ((float*)outv)[(size_t)node * COUT + co] = o;
                }
            }
        }
    }
}

// ---------------- MFMA GEMM v4 (layer 3): A-register-resident, internal N-slice loop ----------------
template <int CIN, int COUT, int NSL>
__global__ __launch_bounds__(256) void k_mm3(const unsigned short* __restrict__ t0,
                                             const unsigned short* __restrict__ t1,
                                             const unsigned short* __restrict__ t2,
                                             const unsigned short* __restrict__ Wt,
                                             const float* __restrict__ bias,
                                             float* __restrict__ out) {
    constexpr int KT = 3 * CIN;              // 384
    constexpr int KP = KT + 8;
    constexpr int NFR = NSL / 16;            // 4
    constexpr int NSLICES = COUT / NSL;      // 4
    constexpr int KSTEPS = KT / 32;          // 12
    __shared__ unsigned short sw[NSL * KP];

    const int tid = threadIdx.x;
    const int wave = tid >> 6, lane = tid & 63;
    const int l16 = lane & 15, quad = lane >> 4;
    const int mBase = blockIdx.x * 128 + wave * 32;
    const int r0 = mBase + l16, r1 = mBase + 16 + l16;
    const bool in0 = r0 < N_NODES, in1 = r1 < N_NODES;

    const unsigned short* tb[3] = {t0, t1, t2};
    const short8 zero8 = {0, 0, 0, 0, 0, 0, 0, 0};

    short8 a0[KSTEPS], a1[KSTEPS];
    #pragma unroll
    for (int kt = 0; kt < KSTEPS; kt++) {
        const int kb = kt * 32;
        const unsigned short* t = tb[kb / CIN];
        const int kin = (kb % CIN) + quad * 8;
        a0[kt] = in0 ? *(const short8*)(t + (size_t)r0 * CIN + kin) : zero8;
        a1[kt] = in1 ? *(const short8*)(t + (size_t)r1 * CIN + kin) : zero8;
    }

    constexpr int CHUNKS = NSL * KT / 8;
    for (int ns = 0; ns < NSLICES; ns++) {
        const int n0 = ns * NSL;
        if (ns) __syncthreads();
        for (int i = tid; i < CHUNKS; i += 256) {
            int row = i / (KT / 8);
            int k8 = i % (KT / 8);
            *(short8*)(sw + row * KP + k8 * 8) =
                *(const short8*)(Wt + (size_t)(n0 + row) * KT + k8 * 8);
        }
        __syncthreads();

        f32x4 acc[2][NFR] = {};
        #pragma unroll
        for (int kt = 0; kt < KSTEPS; kt++) {
            #pragma unroll
            for (int nf = 0; nf < NFR; nf++) {
                const short8 b = *(const short8*)(sw + (nf * 16 + l16) * KP + kt * 32 + quad * 8);
                acc[0][nf] = __builtin_amdgcn_mfma_f32_16x16x32_bf16(a0[kt], b, acc[0][nf], 0, 0, 0);
                acc[1][nf] = __builtin_amdgcn_mfma_f32_16x16x32_bf16(a1[kt], b, acc[1][nf], 0, 0, 0);
            }
        }

        #pragma unroll
        for (int mi = 0; mi < 2; mi++) {
            #pragma unroll
            for (int nf = 0; nf < NFR; nf++) {
                #pragma unroll
                for (int r = 0; r < 4; r++) {
                    const int node = mBase + mi * 16 + quad * 4 + r;
                    if (node < N_NODES) {
                        const int co = n0 + nf * 16 + l16;
                        out[(size_t)node * COUT + co] = acc[mi][nf][r] + bias[co];
                    }
                }
            }
        }
    }
}

// ---------------- launch ----------------
static inline int ceil_div(int a, int b) { return (a + b - 1) / b; }

extern "C" void kernel_launch(void* const* d_in, const int* in_sizes, int n_in,
                              void* d_out, int out_size, void* d_ws, size_t ws_size,
                              hipStream_t stream) {
    const float* x   = (const float*)d_in[0];
    const int*   ei  = (const int*)d_in[1];
    const int*   src = ei;
    const int*   dst = ei + N_EDGES;
    const float* W1 = (const float*)d_in[3];
    const float* b1 = (const float*)d_in[4];
    const float* W2 = (const float*)d_in[5];
    const float* b2 = (const float*)d_in[6];
    const float* W3 = (const float*)d_in[7];
    const float* b3 = (const float*)d_in[8];
    float* out = (float*)d_out;

    // workspace layout (dinv+cnt adjacent -> single memset)
    char* p = (char*)d_ws;
    int*   slots  = (int*)p;             p += (size_t)N_NODES * CAP * 4;
    float* dinv   = (float*)p;           p += (size_t)N_NODES * 4;
    int*   cnt    = (int*)p;             p += (size_t)N_NODES * 4;
    unsigned short* tx1b = (unsigned short*)p; p += (size_t)N_NODES * 128 * 2;
    unsigned short* h1b  = (unsigned short*)p; p += (size_t)N_NODES * 64 * 2;
    unsigned short* tx2b = (unsigned short*)p; p += (size_t)N_NODES * 128 * 2;
    unsigned short* h2b  = (unsigned short*)p; p += (size_t)N_NODES * 128 * 2;
    unsigned short* Wt2  = (unsigned short*)p; p += (size_t)128 * 192 * 2;
    unsigned short* Wt3  = (unsigned short*)p; p += (size_t)256 * 384 * 2;
    // vub [N][192] bf16 (38.4MB) aliases tx2b+h2b (both dead during layer 1)
    unsigned short* vub = tx2b;

    const int TB = 256;
    const int gN = ceil_div(N_NODES, TB);
    const int gG = ceil_div(N_NODES, 8);     // gather: 8 nodes per 256-thr block (2/wave)
    const int gM = ceil_div(N_NODES, 128);   // mm: 128 rows per block
    const int FATB = GB + 3 * GM + 96 + 384;

    // zero dinv+cnt, then fat kernel: build || mm1 || Wt2/Wt3 prep (all independent)
    hipMemsetAsync(dinv, 0, 2 * N_NODES * sizeof(float), stream);
    k_fat<<<FATB, TB, 0, stream>>>(src, dst, dinv, cnt, slots,
                                   x, W1, b1, W2, W3, vub, Wt2, Wt3);
    k_dinv<<<gN, TB, 0, stream>>>(dinv);

    // ---- layer 1 (commuted): h1 = relu( base + P(v + 2 P(u)) ),
    //      [v|u|base] = x @ [W1 | W2 | W0-W2] (+bias on base), props at C=64 ----
    k_gather7<64, false><<<gG, TB, 0, stream>>>(vub + 64, 96, cnt, slots, dinv,
                                                2.f, vub, 96, 1.f, tx1b);
    k_gather7<64, true><<<gG, TB, 0, stream>>>(tx1b, 32, cnt, slots, dinv,
                                               1.f, vub + 128, 96, 1.f, h1b);

    // ---- layer 2: 64 -> 128, relu (props already at min dim) ----
    k_gather7<64, false><<<gG, TB, 0, stream>>>(h1b, 32, cnt, slots, dinv,
                                                1.f, nullptr, 0, 0.f, tx1b);
    k_gather7<64, false><<<gG, TB, 0, stream>>>(tx1b, 32, cnt, slots, dinv,
                                                2.f, h1b, 32, -1.f, tx2b);
    k_mm2<64, 128, 128, true, true><<<dim3(gM, 1), TB, 0, stream>>>(h1b, tx1b, tx2b, Wt2, b2, h2b);

    // ---- layer 3: 128 -> 256, no relu ----
    k_gather7<128, false><<<gG, TB, 0, stream>>>(h2b, 32, cnt, slots, dinv,
                                                 1.f, nullptr, 0, 0.f, tx1b);
    k_gather7<128, false><<<gG, TB, 0, stream>>>(tx1b, 32, cnt, slots, dinv,
                                                 2.f, h2b, 32, -1.f, tx2b);
    k_mm3<128, 256, 64><<<dim3(gM, 1), TB, 0, stream>>>(h2b, tx1b, tx2b, Wt3, b3, out);
}

// Round 7
// 734.837 us; speedup vs baseline: 1.0487x; 1.0487x over previous
//
#include <hip/hip_runtime.h>

#define N_NODES 100000
#define N_EDGES 1600000
#define CAP 64     // max in-degree slots; P(Binom(1.6M,1e-5) >= 64) ~ 3e-22/node
#define GB 6250    // N_EDGES / 256 (exact)
#define GM 782     // ceil(N_NODES / 128)
#define FATB (GB + GM + 96 + 384)   // 7512
#define SWZ 7919   // prime, coprime with FATB -> bijective block swizzle

typedef short short8 __attribute__((ext_vector_type(8)));
typedef float f32x4 __attribute__((ext_vector_type(4)));

__device__ __forceinline__ unsigned short f2b(float f) {
    unsigned u = __builtin_bit_cast(unsigned, f);
    u += 0x7fffu + ((u >> 16) & 1u);          // RNE
    return (unsigned short)(u >> 16);
}
__device__ __forceinline__ float b2f_lo(unsigned p) {
    return __builtin_bit_cast(float, p << 16);
}
__device__ __forceinline__ float b2f_hi(unsigned p) {
    return __builtin_bit_cast(float, p & 0xffff0000u);
}

// ---------------- FAT kernel: CSR build || mm1 || Wt2/Wt3 prep, ROLE-INTERLEAVED ----------------
// Roles are spread through dispatch order by a bijective swizzle so every residency
// generation holds a mix: build's atomic-latency waves co-schedule with mm1's MFMA/HBM
// waves (r6 lesson: in-order roles serialize phases inside the dispatch).
// mm1 loops its 3 output slices internally with A-frags register-resident -> x read once.
__global__ __launch_bounds__(256) void k_fat(const int* __restrict__ src, const int* __restrict__ dst,
                                             float* __restrict__ degout, int* __restrict__ cnt,
                                             int* __restrict__ slots,
                                             const float* __restrict__ x, const float* __restrict__ W1,
                                             const float* __restrict__ b1,
                                             const float* __restrict__ W2, const float* __restrict__ W3,
                                             unsigned short* __restrict__ vub,
                                             unsigned short* __restrict__ Wt2,
                                             unsigned short* __restrict__ Wt3) {
    constexpr int KT = 128, KP = KT + 8, NFR = 4;
    __shared__ unsigned short sw[64 * KP];
    const int tid = threadIdx.x;
    int bid = (int)(((unsigned)blockIdx.x * SWZ) % FATB);

    if (bid < GB) {
        // ---- fused degree-count + direct-slot CSR build (atomic-RMW-bound) ----
        int e = bid * 256 + tid;
        int s = src[e], d = dst[e];
        if (s != d) {
            atomicAdd(&degout[s], 1.0f);
            int pos = atomicAdd(&cnt[d], 1);
            if (pos < CAP) slots[(size_t)d * CAP + pos] = s;   // guard never fires in practice
        }
        return;
    }
    bid -= GB;
    if (bid < GM) {
        // ---- mm1: vub[N][192] = x @ [W1[1] | W1[2] | W1[0]-W1[2]] (+b1 on base cols) ----
        const int wave = tid >> 6, lane = tid & 63;
        const int l16 = lane & 15, quad = lane >> 4;
        const int mBase = bid * 128 + wave * 32;
        const int r0 = mBase + l16, r1 = mBase + 16 + l16;
        const bool in0 = r0 < N_NODES, in1 = r1 < N_NODES;
        const short8 zero8 = {0, 0, 0, 0, 0, 0, 0, 0};

        // A fragments register-resident (x fp32 -> bf16 in-register, read ONCE)
        short8 a0[4], a1[4];
        #pragma unroll
        for (int kt = 0; kt < 4; kt++) {
            const int kin = kt * 32 + quad * 8;
            short8 t0 = zero8, t1 = zero8;
            if (in0) {
                const float* px = x + (size_t)r0 * 128 + kin;
                float4 f0 = *(const float4*)px, f1 = *(const float4*)(px + 4);
                t0[0] = (short)f2b(f0.x); t0[1] = (short)f2b(f0.y);
                t0[2] = (short)f2b(f0.z); t0[3] = (short)f2b(f0.w);
                t0[4] = (short)f2b(f1.x); t0[5] = (short)f2b(f1.y);
                t0[6] = (short)f2b(f1.z); t0[7] = (short)f2b(f1.w);
            }
            if (in1) {
                const float* px = x + (size_t)r1 * 128 + kin;
                float4 f0 = *(const float4*)px, f1 = *(const float4*)(px + 4);
                t1[0] = (short)f2b(f0.x); t1[1] = (short)f2b(f0.y);
                t1[2] = (short)f2b(f0.z); t1[3] = (short)f2b(f0.w);
                t1[4] = (short)f2b(f1.x); t1[5] = (short)f2b(f1.y);
                t1[6] = (short)f2b(f1.z); t1[7] = (short)f2b(f1.w);
            }
            a0[kt] = t0; a1[kt] = t1;
        }

        for (int sl = 0; sl < 3; sl++) {
            const int n0 = sl * 64;
            if (sl) __syncthreads();
            // stage virtual Wt1m rows n0..n0+63 into LDS with inline transform
            // (consecutive 64 threads read consecutive co -> coalesced global)
            for (int i = tid; i < 64 * 128; i += 256) {
                int k = i >> 6;
                int r = i & 63;
                int co = r + n0;
                float v;
                if (co < 64)       v = W1[(128 + k) * 64 + co];
                else if (co < 128) v = W1[(256 + k) * 64 + (co - 64)];
                else               v = W1[k * 64 + (co - 128)] - W1[(256 + k) * 64 + (co - 128)];
                sw[r * KP + k] = f2b(v);
            }
            __syncthreads();

            f32x4 acc[2][NFR] = {};
            #pragma unroll
            for (int kt = 0; kt < 4; kt++) {
                #pragma unroll
                for (int nf = 0; nf < NFR; nf++) {
                    const short8 b = *(const short8*)(sw + (nf * 16 + l16) * KP + kt * 32 + quad * 8);
                    acc[0][nf] = __builtin_amdgcn_mfma_f32_16x16x32_bf16(a0[kt], b, acc[0][nf], 0, 0, 0);
                    acc[1][nf] = __builtin_amdgcn_mfma_f32_16x16x32_bf16(a1[kt], b, acc[1][nf], 0, 0, 0);
                }
            }

            #pragma unroll
            for (int mi = 0; mi < 2; mi++) {
                #pragma unroll
                for (int nf = 0; nf < NFR; nf++) {
                    #pragma unroll
                    for (int r = 0; r < 4; r++) {
                        const int node = mBase + mi * 16 + quad * 4 + r;
                        if (node < N_NODES) {
                            const int co = n0 + nf * 16 + l16;
                            float o = acc[mi][nf][r] + (co >= 128 ? b1[co - 128] : 0.f);
                            vub[(size_t)node * 192 + co] = f2b(o);
                        }
                    }
                }
            }
        }
        return;
    }
    bid -= GM;
    if (bid < 96) {
        // ---- Wt2[128][192] = transpose(W2) bf16 ----
        int j = bid * 256 + tid;                 // < 24576
        int k = j % 192, n = j / 192;
        Wt2[(size_t)n * 192 + k] = f2b(W2[(size_t)k * 128 + n]);
        return;
    }
    bid -= 96;
    {
        // ---- Wt3[256][384] = transpose(W3) bf16 ----
        int j = bid * 256 + tid;                 // < 98304
        int k = j % 384, n = j / 384;
        Wt3[(size_t)n * 384 + k] = f2b(W3[(size_t)k * 256 + n]);
    }
}

__global__ void k_dinv(float* __restrict__ deg) {
    int n = blockIdx.x * blockDim.x + threadIdx.x;
    if (n < N_NODES) {
        float dg = deg[n];
        deg[n] = dg > 0.f ? rsqrtf(dg) : 0.f;
    }
}

// ---------------- gather v7: 8-deep unroll padded to mhi (no serial remainder) ----------------
// out[n] = (-alpha*dinv[n]) * sum_e dinv[c]*h[c]  (+ beta*init[n]); fp32 accum.
// 2 nodes per wave (lanes 0..31 -> n0, 32..63 -> n1). Lanes past a node's degree
// are staged c=0,w=0 -> spurious iterations read L1-hot row 0 and fmaf(0,.) (exact no-op).
template <int C, bool RELU>
__global__ __launch_bounds__(256) void k_gather7(const unsigned short* __restrict__ h,
                                                 int hStride,
                                                 const int* __restrict__ cnt,
                                                 const int* __restrict__ slots,
                                                 const float* __restrict__ dinv,
                                                 float alpha,
                                                 const unsigned short* __restrict__ init,
                                                 int iStride,
                                                 float beta,
                                                 unsigned short* __restrict__ out) {
    const int wave = threadIdx.x >> 6;
    const int lane = threadIdx.x & 63;
    const int half = lane >> 5;
    const int l32  = lane & 31;
    const int n0 = (blockIdx.x * 4 + wave) * 2;   // N_NODES even -> n1 always valid
    if (n0 >= N_NODES) return;
    const int n1 = n0 + 1;
    const int m0 = min(cnt[n0], CAP);
    const int m1 = min(cnt[n1], CAP);
    const int nMy = half ? n1 : n0;

    // full-wave slot staging: lane j holds slot j of each node (c=0,w=0 past degree)
    int c0l = 0, c1l = 0;
    float w0f = 0.f, w1f = 0.f;
    if (lane < m0) { c0l = slots[(size_t)n0 * CAP + lane]; w0f = dinv[c0l]; }
    if (lane < m1) { c1l = slots[(size_t)n1 * CAP + lane]; w1f = dinv[c1l]; }
    const int w0i = __builtin_bit_cast(int, w0f);
    const int w1i = __builtin_bit_cast(int, w1f);

    const int mhi = max(m0, m1);
    const float scale = -alpha * dinv[nMy];

    if (C == 128) {
        const uint2* h4 = (const uint2*)h;
        float ax = 0.f, ay = 0.f, az = 0.f, aw = 0.f;
        for (int j = 0; j < mhi; j += 8) {
            #pragma unroll
            for (int k = 0; k < 8; k++) {
                int cA = __builtin_amdgcn_readlane(c0l, j + k);
                int cB = __builtin_amdgcn_readlane(c1l, j + k);
                float wA = __builtin_bit_cast(float, __builtin_amdgcn_readlane(w0i, j + k));
                float wB = __builtin_bit_cast(float, __builtin_amdgcn_readlane(w1i, j + k));
                int c = half ? cB : cA;
                float w = half ? wB : wA;
                uint2 q = h4[(size_t)c * hStride + l32];
                ax = fmaf(w, b2f_lo(q.x), ax); ay = fmaf(w, b2f_hi(q.x), ay);
                az = fmaf(w, b2f_lo(q.y), az); aw = fmaf(w, b2f_hi(q.y), aw);
            }
        }
        float vx = scale * ax, vy = scale * ay, vz = scale * az, vw = scale * aw;
        if (init) {
            uint2 ip = ((const uint2*)init)[(size_t)nMy * iStride + l32];
            vx = fmaf(beta, b2f_lo(ip.x), vx); vy = fmaf(beta, b2f_hi(ip.x), vy);
            vz = fmaf(beta, b2f_lo(ip.y), vz); vw = fmaf(beta, b2f_hi(ip.y), vw);
        }
        if (RELU) {
            vx = fmaxf(vx, 0.f); vy = fmaxf(vy, 0.f);
            vz = fmaxf(vz, 0.f); vw = fmaxf(vw, 0.f);
        }
        uint2 o;
        o.x = (unsigned)f2b(vx) | ((unsigned)f2b(vy) << 16);
        o.y = (unsigned)f2b(vz) | ((unsigned)f2b(vw) << 16);
        ((uint2*)out)[(size_t)nMy * 32 + l32] = o;
    } else {   // C == 64
        const unsigned* h2 = (const unsigned*)h;
        float ax = 0.f, ay = 0.f;
        for (int j = 0; j < mhi; j += 8) {
            #pragma unroll
            for (int k = 0; k < 8; k++) {
                int cA = __builtin_amdgcn_readlane(c0l, j + k);
                int cB = __builtin_amdgcn_readlane(c1l, j + k);
                float wA = __builtin_bit_cast(float, __builtin_amdgcn_readlane(w0i, j + k));
                float wB = __builtin_bit_cast(float, __builtin_amdgcn_readlane(w1i, j + k));
                int c = half ? cB : cA;
                float w = half ? wB : wA;
                unsigned q = h2[(size_t)c * hStride + l32];
                ax = fmaf(w, b2f_lo(q), ax); ay = fmaf(w, b2f_hi(q), ay);
            }
        }
        float vx = scale * ax, vy = scale * ay;
        if (init) {
            unsigned ip = ((const unsigned*)init)[(size_t)nMy * iStride + l32];
            vx = fmaf(beta, b2f_lo(ip), vx); vy = fmaf(beta, b2f_hi(ip), vy);
        }
        if (RELU) { vx = fmaxf(vx, 0.f); vy = fmaxf(vy, 0.f); }
        ((unsigned*)out)[(size_t)nMy * 32 + l32] =
            (unsigned)f2b(vx) | ((unsigned)f2b(vy) << 16);
    }
}

// ---------------- MFMA GEMM v2: LDS-staged Wt N-slice, 128-row blocks ----------------
template <int CIN, int COUT, int NSL, bool RELU, bool BF16OUT>
__global__ __launch_bounds__(256) void k_mm2(const unsigned short* __restrict__ t0,
                                             const unsigned short* __restrict__ t1,
                                             const unsigned short* __restrict__ t2,
                                             const unsigned short* __restrict__ Wt,
                                             const float* __restrict__ bias,
                                             void* __restrict__ outv) {
    constexpr int KT = 3 * CIN;
    constexpr int KP = KT + 8;
    constexpr int NFR = NSL / 16;
    __shared__ unsigned short sw[NSL * KP];

    const int tid = threadIdx.x;
    const int n0 = blockIdx.y * NSL;

    constexpr int CHUNKS = NSL * KT / 8;
    for (int i = tid; i < CHUNKS; i += 256) {
        int row = i / (KT / 8);
        int k8 = i % (KT / 8);
        short8 v = *(const short8*)(Wt + (size_t)(n0 + row) * KT + k8 * 8);
        *(short8*)(sw + row * KP + k8 * 8) = v;
    }
    __syncthreads();

    const int wave = tid >> 6, lane = tid & 63;
    const int l16 = lane & 15, quad = lane >> 4;
    const int mBase = blockIdx.x * 128 + wave * 32;
    const int r0 = mBase + l16, r1 = mBase + 16 + l16;
    const bool in0 = r0 < N_NODES, in1 = r1 < N_NODES;

    f32x4 acc[2][NFR] = {};
    const unsigned short* tb[3] = {t0, t1, t2};
    const short8 zero8 = {0, 0, 0, 0, 0, 0, 0, 0};

    #pragma unroll
    for (int kt = 0; kt < KT / 32; kt++) {
        const int kb = kt * 32;
        const unsigned short* t = tb[kb / CIN];
        const int kin = (kb % CIN) + quad * 8;
        short8 a0 = zero8, a1 = zero8;
        if (in0) a0 = *(const short8*)(t + (size_t)r0 * CIN + kin);
        if (in1) a1 = *(const short8*)(t + (size_t)r1 * CIN + kin);
        #pragma unroll
        for (int nf = 0; nf < NFR; nf++) {
            const short8 b = *(const short8*)(sw + (nf * 16 + l16) * KP + kb + quad * 8);
            acc[0][nf] = __builtin_amdgcn_mfma_f32_16x16x32_bf16(a0, b, acc[0][nf], 0, 0, 0);
            acc[1][nf] = __builtin_amdgcn_mfma_f32_16x16x32_bf16(a1, b, acc[1][nf], 0, 0, 0);
        }
    }

    #pragma unroll
    for (int mi = 0; mi < 2; mi++) {
        #pragma unroll
        for (int nf = 0; nf < NFR; nf++) {
            #pragma unroll
            for (int r = 0; r < 4; r++) {
                const int node = mBase + mi * 16 + quad * 4 + r;
                if (node < N_NODES) {
                    const int co = n0 + nf * 16 + l16;
                    float o = acc[mi][nf][r] + bias[co];
                    if (RELU) o = fmaxf(o, 0.f);
                    if (BF16OUT)
                        ((unsigned short*)outv)[(size_t)node * COUT + co] = f2b(o);
                    else
                        ((float*)outv)[(size_t)node * COUT + co] = o;
                }
            }
        }
    }
}

// ---------------- MFMA GEMM v4 (layer 3): A-register-resident, internal N-slice loop ----------------
template <int CIN, int COUT, int NSL>
__global__ __launch_bounds__(256) void k_mm3(const unsigned short* __restrict__ t0,
                                             const unsigned short* __restrict__ t1,
                                             const unsigned short* __restrict__ t2,
                                             const unsigned short* __restrict__ Wt,
                                             const float* __restrict__ bias,
                                             float* __restrict__ out) {
    constexpr int KT = 3 * CIN;              // 384
    constexpr int KP = KT + 8;
    constexpr int NFR = NSL / 16;            // 4
    constexpr int NSLICES = COUT / NSL;      // 4
    constexpr int KSTEPS = KT / 32;          // 12
    __shared__ unsigned short sw[NSL * KP];

    const int tid = threadIdx.x;
    const int wave = tid >> 6, lane = tid & 63;
    const int l16 = lane & 15, quad = lane >> 4;
    const int mBase = blockIdx.x * 128 + wave * 32;
    const int r0 = mBase + l16, r1 = mBase + 16 + l16;
    const bool in0 = r0 < N_NODES, in1 = r1 < N_NODES;

    const unsigned short* tb[3] = {t0, t1, t2};
    const short8 zero8 = {0, 0, 0, 0, 0, 0, 0, 0};

    short8 a0[KSTEPS], a1[KSTEPS];
    #pragma unroll
    for (int kt = 0; kt < KSTEPS; kt++) {
        const int kb = kt * 32;
        const unsigned short* t = tb[kb / CIN];
        const int kin = (kb % CIN) + quad * 8;
        a0[kt] = in0 ? *(const short8*)(t + (size_t)r0 * CIN + kin) : zero8;
        a1[kt] = in1 ? *(const short8*)(t + (size_t)r1 * CIN + kin) : zero8;
    }

    constexpr int CHUNKS = NSL * KT / 8;
    for (int ns = 0; ns < NSLICES; ns++) {
        const int n0 = ns * NSL;
        if (ns) __syncthreads();
        for (int i = tid; i < CHUNKS; i += 256) {
            int row = i / (KT / 8);
            int k8 = i % (KT / 8);
            *(short8*)(sw + row * KP + k8 * 8) =
                *(const short8*)(Wt + (size_t)(n0 + row) * KT + k8 * 8);
        }
        __syncthreads();

        f32x4 acc[2][NFR] = {};
        #pragma unroll
        for (int kt = 0; kt < KSTEPS; kt++) {
            #pragma unroll
            for (int nf = 0; nf < NFR; nf++) {
                const short8 b = *(const short8*)(sw + (nf * 16 + l16) * KP + kt * 32 + quad * 8);
                acc[0][nf] = __builtin_amdgcn_mfma_f32_16x16x32_bf16(a0[kt], b, acc[0][nf], 0, 0, 0);
                acc[1][nf] = __builtin_amdgcn_mfma_f32_16x16x32_bf16(a1[kt], b, acc[1][nf], 0, 0, 0);
            }
        }

        #pragma unroll
        for (int mi = 0; mi < 2; mi++) {
            #pragma unroll
            for (int nf = 0; nf < NFR; nf++) {
                #pragma unroll
                for (int r = 0; r < 4; r++) {
                    const int node = mBase + mi * 16 + quad * 4 + r;
                    if (node < N_NODES) {
                        const int co = n0 + nf * 16 + l16;
                        out[(size_t)node * COUT + co] = acc[mi][nf][r] + bias[co];
                    }
                }
            }
        }
    }
}

// ---------------- launch ----------------
static inline int ceil_div(int a, int b) { return (a + b - 1) / b; }

extern "C" void kernel_launch(void* const* d_in, const int* in_sizes, int n_in,
                              void* d_out, int out_size, void* d_ws, size_t ws_size,
                              hipStream_t stream) {
    const float* x   = (const float*)d_in[0];
    const int*   ei  = (const int*)d_in[1];
    const int*   src = ei;
    const int*   dst = ei + N_EDGES;
    const float* W1 = (const float*)d_in[3];
    const float* b1 = (const float*)d_in[4];
    const float* W2 = (const float*)d_in[5];
    const float* b2 = (const float*)d_in[6];
    const float* W3 = (const float*)d_in[7];
    const float* b3 = (const float*)d_in[8];
    float* out = (float*)d_out;

    // workspace layout (dinv+cnt adjacent -> single memset)
    char* p = (char*)d_ws;
    int*   slots  = (int*)p;             p += (size_t)N_NODES * CAP * 4;
    float* dinv   = (float*)p;           p += (size_t)N_NODES * 4;
    int*   cnt    = (int*)p;             p += (size_t)N_NODES * 4;
    unsigned short* tx1b = (unsigned short*)p; p += (size_t)N_NODES * 128 * 2;
    unsigned short* h1b  = (unsigned short*)p; p += (size_t)N_NODES * 64 * 2;
    unsigned short* tx2b = (unsigned short*)p; p += (size_t)N_NODES * 128 * 2;
    unsigned short* h2b  = (unsigned short*)p; p += (size_t)N_NODES * 128 * 2;
    unsigned short* Wt2  = (unsigned short*)p; p += (size_t)128 * 192 * 2;
    unsigned short* Wt3  = (unsigned short*)p; p += (size_t)256 * 384 * 2;
    // vub [N][192] bf16 (38.4MB) aliases tx2b+h2b (both dead during layer 1)
    unsigned short* vub = tx2b;

    const int TB = 256;
    const int gN = ceil_div(N_NODES, TB);
    const int gG = ceil_div(N_NODES, 8);     // gather: 8 nodes per 256-thr block (2/wave)
    const int gM = ceil_div(N_NODES, 128);   // mm: 128 rows per block

    // zero dinv+cnt, then fat kernel: build || mm1 || Wt2/Wt3 prep (role-interleaved)
    hipMemsetAsync(dinv, 0, 2 * N_NODES * sizeof(float), stream);
    k_fat<<<FATB, TB, 0, stream>>>(src, dst, dinv, cnt, slots,
                                   x, W1, b1, W2, W3, vub, Wt2, Wt3);
    k_dinv<<<gN, TB, 0, stream>>>(dinv);

    // ---- layer 1 (commuted): h1 = relu( base + P(v + 2 P(u)) ),
    //      [v|u|base] = x @ [W1 | W2 | W0-W2] (+bias on base), props at C=64 ----
    k_gather7<64, false><<<gG, TB, 0, stream>>>(vub + 64, 96, cnt, slots, dinv,
                                                2.f, vub, 96, 1.f, tx1b);
    k_gather7<64, true><<<gG, TB, 0, stream>>>(tx1b, 32, cnt, slots, dinv,
                                               1.f, vub + 128, 96, 1.f, h1b);

    // ---- layer 2: 64 -> 128, relu (props already at min dim) ----
    k_gather7<64, false><<<gG, TB, 0, stream>>>(h1b, 32, cnt, slots, dinv,
                                                1.f, nullptr, 0, 0.f, tx1b);
    k_gather7<64, false><<<gG, TB, 0, stream>>>(tx1b, 32, cnt, slots, dinv,
                                                2.f, h1b, 32, -1.f, tx2b);
    k_mm2<64, 128, 128, true, true><<<dim3(gM, 1), TB, 0, stream>>>(h1b, tx1b, tx2b, Wt2, b2, h2b);

    // ---- layer 3: 128 -> 256, no relu ----
    k_gather7<128, false><<<gG, TB, 0, stream>>>(h2b, 32, cnt, slots, dinv,
                                                 1.f, nullptr, 0, 0.f, tx1b);
    k_gather7<128, false><<<gG, TB, 0, stream>>>(tx1b, 32, cnt, slots, dinv,
                                                 2.f, h2b, 32, -1.f, tx2b);
    k_mm3<128, 256, 64><<<dim3(gM, 1), TB, 0, stream>>>(h2b, tx1b, tx2b, Wt3, b3, out);
}